// Round 21
// baseline (225.324 us; speedup 1.0000x reference)
//
#include <hip/hip_runtime.h>
#include <hip/hip_bf16.h>
#include <math.h>

// Round 21: fully wave-private hero chain + per-wave x staging.
//  r20: 213us, k12 latency-bound (VALU 31%, MFMA 3%, HBM 20%) -- ~27
//  lockstep barriers serialize staging latency across waves; (256,4)
//  capped occupancy at 4 blocks/CU regardless of the LDS shrink.
//  (a) Each wave stages its OWN tiles' x rows -> stage/L1x5/L2/L3/ho/uv
//      all barrier-free (wave-internal ordering only).
//  (b) Pairs build remapped wave-private (lane builds rows of its wave's
//      tiles; u/v stable) -> 2 barriers/pass. Block: ~27 -> 11 barriers.
//  (c) __launch_bounds__(256,5): cap ~102 >> need ~52 -> 5 blocks/CU.

#define NB 65536
#define SPB 24          // K12
#define SPB3 32         // K3

typedef __attribute__((ext_vector_type(8))) short short8;
typedef __attribute__((ext_vector_type(4))) float f32x4;

__device__ __forceinline__ unsigned bfr(float f) {
    unsigned u = __float_as_uint(f);
    return (u + 0x7fffu + ((u >> 16) & 1u)) >> 16;
}
__device__ __forceinline__ unsigned pack_bf(float a, float b) {
    return bfr(a) | (bfr(b) << 16);
}
__device__ __forceinline__ float bf_lo(unsigned u) { return __uint_as_float(u << 16); }
__device__ __forceinline__ float bf_hi(unsigned u) { return __uint_as_float(u & 0xffff0000u); }

// ========== K12: hero chain + uv + counter pairs + pool (all MFMA) ==========
__global__ __launch_bounds__(256, 5) void k12_hero_counter(
    const float* __restrict__ x,
    const float* __restrict__ h_w1, const float* __restrict__ h_b1,
    const float* __restrict__ h_w2, const float* __restrict__ h_b2,
    const float* __restrict__ h_w3, const float* __restrict__ h_b3,
    const float* __restrict__ c_w1, const float* __restrict__ c_b1,
    const float* __restrict__ c_w2, const float* __restrict__ c_b2,
    const float* __restrict__ c_w3, const float* __restrict__ c_b3,
    unsigned* __restrict__ ho_ws,      // [NB*10][8] u32 (16 bf16/row)
    float* __restrict__ g_ws)          // [NB][8] f32
{
    // [0,4800)     acts u16 [240][40] (x-stage / h1 / h2 / ho / u|v)
    // [4800,7680)  h1p  u16 [240][24] (48B rows); sC = f32 stride-12 alias
    __shared__ unsigned smem_u[7680];
    unsigned short* const acts = (unsigned short*)smem_u;
    unsigned* const h1pU = smem_u + 4800;
    unsigned short* const h1pU16 = (unsigned short*)(smem_u + 4800);
    float* const sC = (float*)(smem_u + 4800);      // stride 12 f32 per row

    const int tid = threadIdx.x;
    const int s0  = blockIdx.x * SPB;
    const int vs  = (NB - s0 < SPB) ? (NB - s0) : SPB;
    const int vr  = vs * 10;

    const int lane = tid & 63;
    const int wv   = tid >> 6;
    const int lm   = lane & 15;
    const int lg   = lane >> 4;
    const short8 zero8 = (short8){0,0,0,0,0,0,0,0};

    // ==== L1: [240x140]@[140x32], wave-private stage + MFMA, NO barriers ====
    f32x4 acc[4][2];
    #pragma unroll
    for (int t = 0; t < 4; ++t) {
        const float b0 = h_b1[lm], b1 = h_b1[16 + lm];
        acc[t][0] = (f32x4){b0, b0, b0, b0};
        acc[t][1] = (f32x4){b1, b1, b1, b1};
    }
    for (int c = 0; c < 5; ++c) {
        short8 w0f, w1f;
        #pragma unroll
        for (int i = 0; i < 8; ++i) {
            const int k = c * 32 + lg * 8 + i;
            w0f[i] = (short)((k < 140) ? bfr(h_w1[k * 32 + lm]) : 0);
            w1f[i] = (short)((k < 140) ? bfr(h_w1[k * 32 + 16 + lm]) : 0);
        }
        // stage: each wave writes its own tiles' rows (chunk c)
        #pragma unroll
        for (int t = 0; t < 4; ++t) {
            const int tl = wv + 4 * t;
            if (tl < 15) {
                #pragma unroll
                for (int h = 0; h < 2; ++h) {
                    const int idx = lane + 64 * h;
                    const int grow = tl * 16 + (idx >> 3);
                    const int q = idx & 7;
                    unsigned lo = 0, hi = 0;
                    if (grow < vr && (c < 4 || q < 3)) {
                        const float4 v = *(const float4*)(
                            x + ((size_t)s0 * 10 + grow) * 140 + c * 32 + q * 4);
                        lo = pack_bf(v.x, v.y);
                        hi = pack_bf(v.z, v.w);
                    }
                    smem_u[grow * 20 + q * 2]     = lo;
                    smem_u[grow * 20 + q * 2 + 1] = hi;
                }
            }
        }
        // MFMA own tiles (wave-internal ds ordering; no barrier)
        #pragma unroll
        for (int t = 0; t < 4; ++t) {
            const int tl = wv + 4 * t;
            if (tl < 15) {
                const short8 af = *(const short8*)(acts + (tl * 16 + lm) * 40 + lg * 8);
                acc[t][0] = __builtin_amdgcn_mfma_f32_16x16x32_bf16(af, w0f, acc[t][0], 0, 0, 0);
                acc[t][1] = __builtin_amdgcn_mfma_f32_16x16x32_bf16(af, w1f, acc[t][1], 0, 0, 0);
            }
        }
    }
    // h1 relu writeback -> own tiles
    #pragma unroll
    for (int t = 0; t < 4; ++t) {
        const int tl = wv + 4 * t;
        if (tl < 15) {
            #pragma unroll
            for (int nt = 0; nt < 2; ++nt)
                #pragma unroll
                for (int r = 0; r < 4; ++r)
                    acts[(tl * 16 + lg * 4 + r) * 40 + nt * 16 + lm] =
                        (unsigned short)bfr(fmaxf(acc[t][nt][r], 0.f));
        }
    }

    // ==== L2: [240x32]@[32x32], in-place, wave-private ====
    {
        short8 af[4];
        #pragma unroll
        for (int t = 0; t < 4; ++t) {
            const int tl = wv + 4 * t;
            af[t] = (tl < 15) ? *(const short8*)(acts + (tl * 16 + lm) * 40 + lg * 8) : zero8;
        }
        short8 w0f, w1f;
        #pragma unroll
        for (int i = 0; i < 8; ++i) {
            const int k = lg * 8 + i;
            w0f[i] = (short)bfr(h_w2[k * 32 + lm]);
            w1f[i] = (short)bfr(h_w2[k * 32 + 16 + lm]);
        }
        #pragma unroll
        for (int t = 0; t < 4; ++t) {
            const float b0 = h_b2[lm], b1 = h_b2[16 + lm];
            f32x4 a20 = (f32x4){b0, b0, b0, b0};
            f32x4 a21 = (f32x4){b1, b1, b1, b1};
            const int tl = wv + 4 * t;
            if (tl < 15) {
                a20 = __builtin_amdgcn_mfma_f32_16x16x32_bf16(af[t], w0f, a20, 0, 0, 0);
                a21 = __builtin_amdgcn_mfma_f32_16x16x32_bf16(af[t], w1f, a21, 0, 0, 0);
                #pragma unroll
                for (int r = 0; r < 4; ++r) {
                    acts[(tl * 16 + lg * 4 + r) * 40 + lm]      =
                        (unsigned short)bfr(fmaxf(a20[r], 0.f));
                    acts[(tl * 16 + lg * 4 + r) * 40 + 16 + lm] =
                        (unsigned short)bfr(fmaxf(a21[r], 0.f));
                }
            }
        }
    }

    // ==== L3: [240x32]@[32x16] linear -> acts cols 0..15, wave-private ====
    {
        short8 af[4];
        #pragma unroll
        for (int t = 0; t < 4; ++t) {
            const int tl = wv + 4 * t;
            af[t] = (tl < 15) ? *(const short8*)(acts + (tl * 16 + lm) * 40 + lg * 8) : zero8;
        }
        short8 w3f;
        #pragma unroll
        for (int i = 0; i < 8; ++i)
            w3f[i] = (short)bfr(h_w3[(lg * 8 + i) * 16 + lm]);
        #pragma unroll
        for (int t = 0; t < 4; ++t) {
            const float b = h_b3[lm];
            f32x4 a3 = (f32x4){b, b, b, b};
            const int tl = wv + 4 * t;
            if (tl < 15) {
                a3 = __builtin_amdgcn_mfma_f32_16x16x32_bf16(af[t], w3f, a3, 0, 0, 0);
                #pragma unroll
                for (int r = 0; r < 4; ++r)
                    acts[(tl * 16 + lg * 4 + r) * 40 + lm] = (unsigned short)bfr(a3[r]);
            }
        }
    }

    // ==== ho writeback: wave-private (reads own tiles' rows) ====
    #pragma unroll
    for (int t = 0; t < 4; ++t) {
        const int tl = wv + 4 * t;
        if (tl < 15) {
            #pragma unroll
            for (int h = 0; h < 2; ++h) {
                const int idx = lane + 64 * h;
                const int grow = tl * 16 + (idx >> 3);
                const int q = idx & 7;
                if (grow < vr)
                    ho_ws[((size_t)s0 * 10 + grow) * 8 + q] = smem_u[grow * 20 + q];
            }
        }
    }

    // ==== uv via MFMA: [240x16]@[16x32] (K pad 32), wave-private ====
    {
        short8 af[4];
        #pragma unroll
        for (int t = 0; t < 4; ++t) {
            const int tl = wv + 4 * t;
            af[t] = (tl < 15 && lg < 2)
                ? *(const short8*)(acts + (tl * 16 + lm) * 40 + lg * 8) : zero8;
        }
        short8 wuf, wvf;
        #pragma unroll
        for (int i = 0; i < 8; ++i) {
            const int k = lg * 8 + i;
            wuf[i] = (short)((k < 16) ? bfr(c_w1[k * 16 + lm]) : 0);
            wvf[i] = (short)((k < 16) ? bfr(c_w1[(16 + k) * 16 + lm]) : 0);
        }
        #pragma unroll
        for (int t = 0; t < 4; ++t) {
            const int tl = wv + 4 * t;
            if (tl < 15) {
                f32x4 au = (f32x4){0.f, 0.f, 0.f, 0.f};
                f32x4 av = (f32x4){0.f, 0.f, 0.f, 0.f};
                au = __builtin_amdgcn_mfma_f32_16x16x32_bf16(af[t], wuf, au, 0, 0, 0);
                av = __builtin_amdgcn_mfma_f32_16x16x32_bf16(af[t], wvf, av, 0, 0, 0);
                #pragma unroll
                for (int r = 0; r < 4; ++r) {
                    const int row = tl * 16 + lg * 4 + r;
                    acts[row * 40 + lm]      = (unsigned short)bfr(au[r]); // u
                    acts[row * 40 + 16 + lm] = (unsigned short)bfr(av[r]); // v
                }
            }
        }
    }
    __syncthreads();                 // u/v visible block-wide (pairs cross-read)

    // ==== counter pairs: 5 passes, 2 barriers/pass ====
    float m00 = -1e30f, m01 = -1e30f, m02 = -1e30f, m03 = -1e30f;
    float m10 = -1e30f, m11 = -1e30f, m12 = -1e30f, m13 = -1e30f;
    short8 cw2f, cw3f;               // hoisted (constant across passes)
    #pragma unroll
    for (int i = 0; i < 8; ++i) {
        const int k = lg * 8 + i;
        cw2f[i] = (short)((k < 16) ? bfr(c_w2[k * 16 + lm]) : 0);
        cw3f[i] = (short)((k < 16 && lm < 8) ? bfr(c_w3[k * 8 + lm]) : 0);
    }
    const int btl = wv + 4 * lg;     // lane's build tile
    for (int p = 0; p < 5; ++p) {
        // build h1p: WAVE-PRIVATE rows (lane builds row btl*16+lm);
        // reads u/v cross-wave but those are stable (read-only here).
        if (btl < 15) {
            const int row = btl * 16 + lm;
            if (row < vr) {
                const int s = row / 10, t10 = row % 10;
                const int pr = p * 10 + t10;
                int i, j;
                if (pr < 25) { i = pr / 5; j = 5 + pr % 5; }
                else { const int q = pr - 25; i = 5 + q / 5; j = q % 5; }
                const unsigned* ur  = smem_u + (s * 10 + i) * 20;
                const unsigned* vr2 = smem_u + (s * 10 + j) * 20 + 8;
                #pragma unroll
                for (int cc = 0; cc < 8; ++cc) {
                    const unsigned uu = ur[cc], vv = vr2[cc];
                    const float a = fmaxf(bf_lo(uu) + bf_lo(vv) + c_b1[2 * cc], 0.f);
                    const float b = fmaxf(bf_hi(uu) + bf_hi(vv) + c_b1[2 * cc + 1], 0.f);
                    h1pU[row * 12 + cc] = pack_bf(a, b);
                }
            }
        }
        // counter L2+L3 on own tiles (build was same-wave: no barrier)
        #pragma unroll
        for (int t = 0; t < 4; ++t) {
            const int tl = wv + 4 * t;
            if (tl < 15) {
                const short8 af2 = (lg < 2)
                    ? *(const short8*)(h1pU16 + (tl * 16 + lm) * 24 + lg * 8) : zero8;
                const float b2 = c_b2[lm];
                f32x4 a2 = (f32x4){b2, b2, b2, b2};
                a2 = __builtin_amdgcn_mfma_f32_16x16x32_bf16(af2, cw2f, a2, 0, 0, 0);
                #pragma unroll
                for (int r = 0; r < 4; ++r)
                    h1pU16[(tl * 16 + lg * 4 + r) * 24 + lm] =
                        (unsigned short)bfr(fmaxf(a2[r], 0.f));
                const short8 af3 = (lg < 2)
                    ? *(const short8*)(h1pU16 + (tl * 16 + lm) * 24 + lg * 8) : zero8;
                const float b3 = (lm < 8) ? c_b3[lm] : 0.f;
                f32x4 a3 = (f32x4){b3, b3, b3, b3};
                a3 = __builtin_amdgcn_mfma_f32_16x16x32_bf16(af3, cw3f, a3, 0, 0, 0);
                if (lm < 8) {
                    #pragma unroll
                    for (int r = 0; r < 4; ++r)
                        sC[(tl * 16 + lg * 4 + r) * 12 + lm] = a3[r];
                }
            }
        }
        __syncthreads();             // sC visible for cross-wave pool

        // pool2 + running max (half-aware)
        if (tid < vs * 10) {
            const float* cr = sC + tid * 12;
            const float p0 = fmaxf(cr[0], cr[1]);
            const float p1 = fmaxf(cr[2], cr[3]);
            const float p2 = fmaxf(cr[4], cr[5]);
            const float p3 = fmaxf(cr[6], cr[7]);
            const int pr = p * 10 + tid % 10;
            if (pr < 25) {
                m00 = fmaxf(m00, p0); m01 = fmaxf(m01, p1);
                m02 = fmaxf(m02, p2); m03 = fmaxf(m03, p3);
            } else {
                m10 = fmaxf(m10, p0); m11 = fmaxf(m11, p1);
                m12 = fmaxf(m12, p2); m13 = fmaxf(m13, p3);
            }
        }
        __syncthreads();             // pool reads done before next build (alias)
    }

    // ==== final reduce over the 10 t-lanes -> g ====
    if (tid < vs * 10) {
        float* dst = sC + tid * 12;
        dst[0] = m00; dst[1] = m01; dst[2] = m02; dst[3] = m03;
        dst[4] = m10; dst[5] = m11; dst[6] = m12; dst[7] = m13;
    }
    __syncthreads();
    if (tid < vs * 8) {
        const int s = tid >> 3, r = tid & 7;
        float mx = -1e30f;
        #pragma unroll
        for (int t = 0; t < 10; ++t)
            mx = fmaxf(mx, sC[(s * 10 + t) * 12 + r]);
        g_ws[(size_t)(s0 + s) * 8 + r] = mx;
    }
}

// ================= K3: team (MFMA) + final MLP -> out ==================
__global__ __launch_bounds__(256, 4) void k3_team(
    const unsigned* __restrict__ ho_ws,
    const float* __restrict__ g_ws,
    const float* __restrict__ t_w1, const float* __restrict__ t_b1,
    const float* __restrict__ t_w2, const float* __restrict__ t_b2,
    const float* __restrict__ t_w3, const float* __restrict__ t_b3,
    const float* __restrict__ f_w1, const float* __restrict__ f_b1,
    const float* __restrict__ f_w2, const float* __restrict__ f_b2,
    const float* __restrict__ f_w3, const float* __restrict__ f_b3,
    float* __restrict__ out)
{
    __shared__ unsigned smem_u[3328 + 1056];
    unsigned* const acts = smem_u;
    unsigned short* const aU = (unsigned short*)smem_u;
    float* const sT = (float*)(smem_u + 3328);

    const int tid = threadIdx.x;
    const int s0  = blockIdx.x * SPB3;

    const int lane = tid & 63;
    const int wv   = tid >> 6;
    const int lm   = lane & 15;
    const int lg   = lane >> 4;

    for (int j = tid; j < 64 * 52; j += 256) {
        const int row = j / 52, q = j % 52;
        const int s = row >> 1, half = row & 1;
        unsigned val = 0;
        if (q < 40) {
            const int hh = q >> 3, qq = q & 7;
            val = ho_ws[((size_t)(s0 + s) * 10 + half * 5 + hh) * 8 + qq];
        } else if (q < 42) {
            const float* gp = g_ws + (size_t)(s0 + s) * 8 + half * 4 + (q - 40) * 2;
            val = pack_bf(gp[0], gp[1]);
        }
        acts[row * 52 + q] = val;
    }
    __syncthreads();

    // team L1: [64x84]@[84x64], K padded to 96
    f32x4 a1[4];
    #pragma unroll
    for (int nt = 0; nt < 4; ++nt) {
        const float b = t_b1[nt * 16 + lm];
        a1[nt] = (f32x4){b, b, b, b};
    }
    for (int c = 0; c < 3; ++c) {
        const short8 af = *(const short8*)(aU + (wv * 16 + lm) * 104 + c * 32 + lg * 8);
        #pragma unroll
        for (int nt = 0; nt < 4; ++nt) {
            short8 wf;
            #pragma unroll
            for (int i = 0; i < 8; ++i) {
                const int k = c * 32 + lg * 8 + i;
                wf[i] = (short)((k < 84) ? bfr(t_w1[k * 64 + nt * 16 + lm]) : 0);
            }
            a1[nt] = __builtin_amdgcn_mfma_f32_16x16x32_bf16(af, wf, a1[nt], 0, 0, 0);
        }
    }
    #pragma unroll
    for (int nt = 0; nt < 4; ++nt)
        #pragma unroll
        for (int r = 0; r < 4; ++r)
            aU[(wv * 16 + lg * 4 + r) * 104 + nt * 16 + lm] =
                (unsigned short)bfr(fmaxf(a1[nt][r], 0.f));

    // team L2: [64x64]@[64x64]  (wave-private rows)
    f32x4 a2[4];
    #pragma unroll
    for (int nt = 0; nt < 4; ++nt) {
        const float b = t_b2[nt * 16 + lm];
        a2[nt] = (f32x4){b, b, b, b};
    }
    for (int c = 0; c < 2; ++c) {
        const short8 af = *(const short8*)(aU + (wv * 16 + lm) * 104 + c * 32 + lg * 8);
        #pragma unroll
        for (int nt = 0; nt < 4; ++nt) {
            short8 wf;
            #pragma unroll
            for (int i = 0; i < 8; ++i) {
                const int k = c * 32 + lg * 8 + i;
                wf[i] = (short)bfr(t_w2[k * 64 + nt * 16 + lm]);
            }
            a2[nt] = __builtin_amdgcn_mfma_f32_16x16x32_bf16(af, wf, a2[nt], 0, 0, 0);
        }
    }
    #pragma unroll
    for (int nt = 0; nt < 4; ++nt)
        #pragma unroll
        for (int r = 0; r < 4; ++r)
            aU[(wv * 16 + lg * 4 + r) * 104 + nt * 16 + lm] =
                (unsigned short)bfr(fmaxf(a2[nt][r], 0.f));

    // team L3: [64x64]@[64x16] linear
    {
        const float b = t_b3[lm];
        f32x4 a3 = (f32x4){b, b, b, b};
        for (int c = 0; c < 2; ++c) {
            const short8 af = *(const short8*)(aU + (wv * 16 + lm) * 104 + c * 32 + lg * 8);
            short8 wf;
            #pragma unroll
            for (int i = 0; i < 8; ++i) {
                const int k = c * 32 + lg * 8 + i;
                wf[i] = (short)bfr(t_w3[k * 16 + lm]);
            }
            a3 = __builtin_amdgcn_mfma_f32_16x16x32_bf16(af, wf, a3, 0, 0, 0);
        }
        #pragma unroll
        for (int r = 0; r < 4; ++r) {
            const int row = wv * 16 + lg * 4 + r;
            sT[(row >> 1) * 33 + (row & 1) * 16 + lm] = a3[r];
        }
    }
    __syncthreads();

    // F: final MLP + softmax
    if (tid < SPB3) {
        const float* tr = sT + tid * 33;
        float g1[16];
        #pragma unroll
        for (int o = 0; o < 16; ++o) g1[o] = f_b1[o];
        #pragma unroll
        for (int k = 0; k < 32; ++k) {
            const float hk = tr[k];
            const float* wr = f_w1 + k * 16;
            #pragma unroll
            for (int o = 0; o < 16; ++o) g1[o] = fmaf(hk, wr[o], g1[o]);
        }
        float g2[16];
        #pragma unroll
        for (int o = 0; o < 16; ++o) g2[o] = f_b2[o];
        #pragma unroll
        for (int k = 0; k < 16; ++k) {
            const float hk = fmaxf(g1[k], 0.f);
            const float* wr = f_w2 + k * 16;
            #pragma unroll
            for (int o = 0; o < 16; ++o) g2[o] = fmaf(hk, wr[o], g2[o]);
        }
        float l0 = f_b3[0], l1 = f_b3[1];
        #pragma unroll
        for (int k = 0; k < 16; ++k) {
            const float hk = fmaxf(g2[k], 0.f);
            l0 = fmaf(hk, f_w3[2 * k], l0);
            l1 = fmaf(hk, f_w3[2 * k + 1], l1);
        }
        const float e = expf(l1 - l0);
        const float p0 = 1.f / (1.f + e);
        out[(size_t)(s0 + tid) * 2]     = p0;
        out[(size_t)(s0 + tid) * 2 + 1] = 1.f - p0;
    }
}

extern "C" void kernel_launch(void* const* d_in, const int* in_sizes, int n_in,
                              void* d_out, int out_size, void* d_ws, size_t ws_size,
                              hipStream_t stream) {
    (void)in_sizes; (void)n_in; (void)out_size; (void)ws_size;
    const float* x    = (const float*)d_in[0];
    const float* h_w1 = (const float*)d_in[1];  const float* h_b1 = (const float*)d_in[2];
    const float* h_w2 = (const float*)d_in[3];  const float* h_b2 = (const float*)d_in[4];
    const float* h_w3 = (const float*)d_in[5];  const float* h_b3 = (const float*)d_in[6];
    const float* c_w1 = (const float*)d_in[7];  const float* c_b1 = (const float*)d_in[8];
    const float* c_w2 = (const float*)d_in[9];  const float* c_b2 = (const float*)d_in[10];
    const float* c_w3 = (const float*)d_in[11]; const float* c_b3 = (const float*)d_in[12];
    const float* t_w1 = (const float*)d_in[13]; const float* t_b1 = (const float*)d_in[14];
    const float* t_w2 = (const float*)d_in[15]; const float* t_b2 = (const float*)d_in[16];
    const float* t_w3 = (const float*)d_in[17]; const float* t_b3 = (const float*)d_in[18];
    const float* f_w1 = (const float*)d_in[19]; const float* f_b1 = (const float*)d_in[20];
    const float* f_w2 = (const float*)d_in[21]; const float* f_b2 = (const float*)d_in[22];
    const float* f_w3 = (const float*)d_in[23]; const float* f_b3 = (const float*)d_in[24];
    float* out = (float*)d_out;

    unsigned* ho_ws = (unsigned*)d_ws;
    float*    g_ws  = (float*)((char*)d_ws + (size_t)NB * 10 * 8 * 4);

    const int grid12 = (NB + SPB - 1) / SPB;    // 2731
    const int grid3  = NB / SPB3;               // 2048

    k12_hero_counter<<<grid12, 256, 0, stream>>>(
        x, h_w1, h_b1, h_w2, h_b2, h_w3, h_b3,
        c_w1, c_b1, c_w2, c_b2, c_w3, c_b3, ho_ws, g_ws);
    k3_team<<<grid3, 256, 0, stream>>>(ho_ws, g_ws,
        t_w1, t_b1, t_w2, t_b2, t_w3, t_b3,
        f_w1, f_b1, f_w2, f_b2, f_w3, f_b3, out);
}

// Round 22
// 195.253 us; speedup vs baseline: 1.1540x; 1.1540x over previous
//
#include <hip/hip_runtime.h>
#include <hip/hip_bf16.h>
#include <math.h>

// Round 22: FULL fusion -- team+final merged into k12 (r20 base).
//  r20/r21: k12-internal tuning plateaued (213/217us); the k12<->k3 split
//  costs ~25-35us (21MB ho write+read, g round trip, 2nd launch) for data
//  the block already owns. Merge: ho kept in 8 packed VGPRs (horeg, static
//  indexed) from hero-L3 to team phase; after pairs, block writes its 48
//  team rows [48][104]u16 into dead h1p region, 3 waves run the k3-proven
//  team MFMA chain, sT in dead acts region, 24 lanes do final+softmax.

#define NB 65536
#define SPB 24

typedef __attribute__((ext_vector_type(8))) short short8;
typedef __attribute__((ext_vector_type(4))) float f32x4;

__device__ __forceinline__ unsigned bfr(float f) {
    unsigned u = __float_as_uint(f);
    return (u + 0x7fffu + ((u >> 16) & 1u)) >> 16;
}
__device__ __forceinline__ unsigned pack_bf(float a, float b) {
    return bfr(a) | (bfr(b) << 16);
}
__device__ __forceinline__ float bf_lo(unsigned u) { return __uint_as_float(u << 16); }
__device__ __forceinline__ float bf_hi(unsigned u) { return __uint_as_float(u & 0xffff0000u); }

__global__ __launch_bounds__(256, 4) void fused_all(
    const float* __restrict__ x,
    const float* __restrict__ h_w1, const float* __restrict__ h_b1,
    const float* __restrict__ h_w2, const float* __restrict__ h_b2,
    const float* __restrict__ h_w3, const float* __restrict__ h_b3,
    const float* __restrict__ c_w1, const float* __restrict__ c_b1,
    const float* __restrict__ c_w2, const float* __restrict__ c_b2,
    const float* __restrict__ c_w3, const float* __restrict__ c_b3,
    const float* __restrict__ t_w1, const float* __restrict__ t_b1,
    const float* __restrict__ t_w2, const float* __restrict__ t_b2,
    const float* __restrict__ t_w3, const float* __restrict__ t_b3,
    const float* __restrict__ f_w1, const float* __restrict__ f_b1,
    const float* __restrict__ f_w2, const float* __restrict__ f_b2,
    const float* __restrict__ f_w3, const float* __restrict__ f_b3,
    float* __restrict__ out)
{
    // [0,4800)    acts u16 [240][40] (x / h1 / h2 / ho / u|v); later sT f32 [24][33]
    // [4800,7680) h1p u16 [240][24]; sC f32 stride-12 alias; later team
    //             staging u16 [48][104] (2496 u32, ends 7296)
    __shared__ unsigned smem_u[7680];
    unsigned short* const acts = (unsigned short*)smem_u;
    unsigned* const h1pU = smem_u + 4800;
    unsigned short* const h1pU16 = (unsigned short*)(smem_u + 4800);
    float* const sC = (float*)(smem_u + 4800);              // stride 12 f32
    unsigned short* const tmS = (unsigned short*)(smem_u + 4800);  // team staging
    float* const sT = (float*)smem_u;                        // [24][33] f32

    const int tid = threadIdx.x;
    const int s0  = blockIdx.x * SPB;
    const int vs  = (NB - s0 < SPB) ? (NB - s0) : SPB;
    const int vr  = vs * 10;

    const int lane = tid & 63;
    const int wv   = tid >> 6;
    const int lm   = lane & 15;
    const int lg   = lane >> 4;
    const short8 zero8 = (short8){0,0,0,0,0,0,0,0};

    // ==== hero L1: [240x140]@[140x32], tid-striped staging (r20) ====
    f32x4 acc[4][2];
    #pragma unroll
    for (int t = 0; t < 4; ++t) {
        const float b0 = h_b1[lm], b1 = h_b1[16 + lm];
        acc[t][0] = (f32x4){b0, b0, b0, b0};
        acc[t][1] = (f32x4){b1, b1, b1, b1};
    }
    for (int c = 0; c < 5; ++c) {
        short8 w0f, w1f;
        #pragma unroll
        for (int i = 0; i < 8; ++i) {
            const int k = c * 32 + lg * 8 + i;
            w0f[i] = (short)((k < 140) ? bfr(h_w1[k * 32 + lm]) : 0);
            w1f[i] = (short)((k < 140) ? bfr(h_w1[k * 32 + 16 + lm]) : 0);
        }
        for (int j = tid; j < vr * 8; j += 256) {
            const int row = j >> 3, q = j & 7;
            unsigned lo = 0, hi = 0;
            if (c < 4 || q < 3) {
                const float4 v = *(const float4*)(
                    x + ((size_t)s0 * 10 + row) * 140 + c * 32 + q * 4);
                lo = pack_bf(v.x, v.y);
                hi = pack_bf(v.z, v.w);
            }
            smem_u[row * 20 + q * 2]     = lo;
            smem_u[row * 20 + q * 2 + 1] = hi;
        }
        __syncthreads();
        #pragma unroll
        for (int t = 0; t < 4; ++t) {
            const int tl = wv + 4 * t;
            if (tl < 15) {
                const short8 af = *(const short8*)(acts + (tl * 16 + lm) * 40 + lg * 8);
                acc[t][0] = __builtin_amdgcn_mfma_f32_16x16x32_bf16(af, w0f, acc[t][0], 0, 0, 0);
                acc[t][1] = __builtin_amdgcn_mfma_f32_16x16x32_bf16(af, w1f, acc[t][1], 0, 0, 0);
            }
        }
        __syncthreads();
    }
    // h1 relu -> own tiles (wave-private)
    #pragma unroll
    for (int t = 0; t < 4; ++t) {
        const int tl = wv + 4 * t;
        if (tl < 15) {
            #pragma unroll
            for (int nt = 0; nt < 2; ++nt)
                #pragma unroll
                for (int r = 0; r < 4; ++r)
                    acts[(tl * 16 + lg * 4 + r) * 40 + nt * 16 + lm] =
                        (unsigned short)bfr(fmaxf(acc[t][nt][r], 0.f));
        }
    }

    // ==== hero L2: wave-private, in-place ====
    {
        short8 af[4];
        #pragma unroll
        for (int t = 0; t < 4; ++t) {
            const int tl = wv + 4 * t;
            af[t] = (tl < 15) ? *(const short8*)(acts + (tl * 16 + lm) * 40 + lg * 8) : zero8;
        }
        short8 w0f, w1f;
        #pragma unroll
        for (int i = 0; i < 8; ++i) {
            const int k = lg * 8 + i;
            w0f[i] = (short)bfr(h_w2[k * 32 + lm]);
            w1f[i] = (short)bfr(h_w2[k * 32 + 16 + lm]);
        }
        #pragma unroll
        for (int t = 0; t < 4; ++t) {
            const float b0 = h_b2[lm], b1 = h_b2[16 + lm];
            f32x4 a20 = (f32x4){b0, b0, b0, b0};
            f32x4 a21 = (f32x4){b1, b1, b1, b1};
            const int tl = wv + 4 * t;
            if (tl < 15) {
                a20 = __builtin_amdgcn_mfma_f32_16x16x32_bf16(af[t], w0f, a20, 0, 0, 0);
                a21 = __builtin_amdgcn_mfma_f32_16x16x32_bf16(af[t], w1f, a21, 0, 0, 0);
                #pragma unroll
                for (int r = 0; r < 4; ++r) {
                    acts[(tl * 16 + lg * 4 + r) * 40 + lm]      =
                        (unsigned short)bfr(fmaxf(a20[r], 0.f));
                    acts[(tl * 16 + lg * 4 + r) * 40 + 16 + lm] =
                        (unsigned short)bfr(fmaxf(a21[r], 0.f));
                }
            }
        }
    }

    // ==== hero L3 -> acts cols 0..15 AND horeg (packed, static-indexed) ====
    unsigned horeg[4][2];
    {
        short8 af[4];
        #pragma unroll
        for (int t = 0; t < 4; ++t) {
            const int tl = wv + 4 * t;
            af[t] = (tl < 15) ? *(const short8*)(acts + (tl * 16 + lm) * 40 + lg * 8) : zero8;
        }
        short8 w3f;
        #pragma unroll
        for (int i = 0; i < 8; ++i)
            w3f[i] = (short)bfr(h_w3[(lg * 8 + i) * 16 + lm]);
        #pragma unroll
        for (int t = 0; t < 4; ++t) {
            const float b = h_b3[lm];
            f32x4 a3 = (f32x4){b, b, b, b};
            const int tl = wv + 4 * t;
            horeg[t][0] = 0; horeg[t][1] = 0;
            if (tl < 15) {
                a3 = __builtin_amdgcn_mfma_f32_16x16x32_bf16(af[t], w3f, a3, 0, 0, 0);
                #pragma unroll
                for (int r = 0; r < 4; ++r)
                    acts[(tl * 16 + lg * 4 + r) * 40 + lm] = (unsigned short)bfr(a3[r]);
                horeg[t][0] = pack_bf(a3[0], a3[1]);
                horeg[t][1] = pack_bf(a3[2], a3[3]);
            }
        }
    }

    // ==== uv via MFMA (wave-private; reads own ho just written) ====
    {
        short8 af[4];
        #pragma unroll
        for (int t = 0; t < 4; ++t) {
            const int tl = wv + 4 * t;
            af[t] = (tl < 15 && lg < 2)
                ? *(const short8*)(acts + (tl * 16 + lm) * 40 + lg * 8) : zero8;
        }
        short8 wuf, wvf;
        #pragma unroll
        for (int i = 0; i < 8; ++i) {
            const int k = lg * 8 + i;
            wuf[i] = (short)((k < 16) ? bfr(c_w1[k * 16 + lm]) : 0);
            wvf[i] = (short)((k < 16) ? bfr(c_w1[(16 + k) * 16 + lm]) : 0);
        }
        #pragma unroll
        for (int t = 0; t < 4; ++t) {
            const int tl = wv + 4 * t;
            if (tl < 15) {
                f32x4 au = (f32x4){0.f, 0.f, 0.f, 0.f};
                f32x4 av = (f32x4){0.f, 0.f, 0.f, 0.f};
                au = __builtin_amdgcn_mfma_f32_16x16x32_bf16(af[t], wuf, au, 0, 0, 0);
                av = __builtin_amdgcn_mfma_f32_16x16x32_bf16(af[t], wvf, av, 0, 0, 0);
                #pragma unroll
                for (int r = 0; r < 4; ++r) {
                    const int row = tl * 16 + lg * 4 + r;
                    acts[row * 40 + lm]      = (unsigned short)bfr(au[r]);
                    acts[row * 40 + 16 + lm] = (unsigned short)bfr(av[r]);
                }
            }
        }
    }
    __syncthreads();                 // u/v visible block-wide

    // ==== counter pairs: 5 passes (r20 structure) ====
    float m00 = -1e30f, m01 = -1e30f, m02 = -1e30f, m03 = -1e30f;
    float m10 = -1e30f, m11 = -1e30f, m12 = -1e30f, m13 = -1e30f;
    short8 cw2f, cw3f;
    #pragma unroll
    for (int i = 0; i < 8; ++i) {
        const int k = lg * 8 + i;
        cw2f[i] = (short)((k < 16) ? bfr(c_w2[k * 16 + lm]) : 0);
        cw3f[i] = (short)((k < 16 && lm < 8) ? bfr(c_w3[k * 8 + lm]) : 0);
    }
    for (int p = 0; p < 5; ++p) {
        if (tid < vs * 10) {
            const int s = tid / 10, t10 = tid % 10;
            const int pr = p * 10 + t10;
            int i, j;
            if (pr < 25) { i = pr / 5; j = 5 + pr % 5; }
            else { const int q = pr - 25; i = 5 + q / 5; j = q % 5; }
            const unsigned* ur  = smem_u + (s * 10 + i) * 20;
            const unsigned* vr2 = smem_u + (s * 10 + j) * 20 + 8;
            #pragma unroll
            for (int cc = 0; cc < 8; ++cc) {
                const unsigned uu = ur[cc], vv = vr2[cc];
                const float a = fmaxf(bf_lo(uu) + bf_lo(vv) + c_b1[2 * cc], 0.f);
                const float b = fmaxf(bf_hi(uu) + bf_hi(vv) + c_b1[2 * cc + 1], 0.f);
                h1pU[tid * 12 + cc] = pack_bf(a, b);
            }
        }
        __syncthreads();

        #pragma unroll
        for (int t = 0; t < 4; ++t) {
            const int tl = wv + 4 * t;
            if (tl < 15) {
                const short8 af2 = (lg < 2)
                    ? *(const short8*)(h1pU16 + (tl * 16 + lm) * 24 + lg * 8) : zero8;
                const float b2 = c_b2[lm];
                f32x4 a2 = (f32x4){b2, b2, b2, b2};
                a2 = __builtin_amdgcn_mfma_f32_16x16x32_bf16(af2, cw2f, a2, 0, 0, 0);
                #pragma unroll
                for (int r = 0; r < 4; ++r)
                    h1pU16[(tl * 16 + lg * 4 + r) * 24 + lm] =
                        (unsigned short)bfr(fmaxf(a2[r], 0.f));
                const short8 af3 = (lg < 2)
                    ? *(const short8*)(h1pU16 + (tl * 16 + lm) * 24 + lg * 8) : zero8;
                const float b3 = (lm < 8) ? c_b3[lm] : 0.f;
                f32x4 a3 = (f32x4){b3, b3, b3, b3};
                a3 = __builtin_amdgcn_mfma_f32_16x16x32_bf16(af3, cw3f, a3, 0, 0, 0);
                if (lm < 8) {
                    #pragma unroll
                    for (int r = 0; r < 4; ++r)
                        sC[(tl * 16 + lg * 4 + r) * 12 + lm] = a3[r];
                }
            }
        }
        __syncthreads();

        if (tid < vs * 10) {
            const float* cr = sC + tid * 12;
            const float p0 = fmaxf(cr[0], cr[1]);
            const float p1 = fmaxf(cr[2], cr[3]);
            const float p2 = fmaxf(cr[4], cr[5]);
            const float p3 = fmaxf(cr[6], cr[7]);
            const int pr = p * 10 + tid % 10;
            if (pr < 25) {
                m00 = fmaxf(m00, p0); m01 = fmaxf(m01, p1);
                m02 = fmaxf(m02, p2); m03 = fmaxf(m03, p3);
            } else {
                m10 = fmaxf(m10, p0); m11 = fmaxf(m11, p1);
                m12 = fmaxf(m12, p2); m13 = fmaxf(m13, p3);
            }
        }
        __syncthreads();
    }

    // ==== g: partial stage -> reduce to register ====
    if (tid < vs * 10) {
        float* dst = sC + tid * 12;
        dst[0] = m00; dst[1] = m01; dst[2] = m02; dst[3] = m03;
        dst[4] = m10; dst[5] = m11; dst[6] = m12; dst[7] = m13;
    }
    __syncthreads();
    float gval = 0.f;
    if (tid < vs * 8) {
        const int s = tid >> 3, r = tid & 7;
        float mx = -1e30f;
        #pragma unroll
        for (int t = 0; t < 10; ++t)
            mx = fmaxf(mx, sC[(s * 10 + t) * 12 + r]);
        gval = mx;
    }
    __syncthreads();                 // all sC reads done before team staging

    // ==== team staging [48][104]u16 over dead h1p/sC region ====
    for (int j = tid; j < 48 * 6; j += 256) {      // zero pad cols u32 46..51? no:
        const int row = j / 6, q = 46 + j % 6;     // u16 cols 92..103 unused pad
        ((unsigned*)tmS)[row * 52 + q] = 0;        // also covers alignment pad
    }
    for (int j = tid; j < 48 * 4; j += 256) {      // zero u16 cols 84..91 (K pad)
        const int row = j / 4, q = 42 + j % 4;
        ((unsigned*)tmS)[row * 52 + q] = 0;
    }
    // ho scatter from horeg: grow=tl*16+lg*4+r -> (tr, col)
    #pragma unroll
    for (int t = 0; t < 4; ++t) {
        const int tl = wv + 4 * t;
        if (tl < 15) {
            #pragma unroll
            for (int r = 0; r < 4; ++r) {
                const int grow = tl * 16 + lg * 4 + r;
                if (grow < vr) {
                    const int s = grow / 10, h = grow % 10;
                    const int tr = s * 2 + (h >= 5);
                    const int col = (h % 5) * 16 + lm;
                    const unsigned pk = horeg[t][r >> 1];
                    const unsigned short hv = (unsigned short)((r & 1) ? (pk >> 16) : (pk & 0xffff));
                    tmS[tr * 104 + col] = hv;
                }
            }
        }
    }
    if (tid < vs * 8) {              // g -> cols 80..83
        const int s = tid >> 3, r = tid & 7;
        const int tr = s * 2 + (r >> 2);
        tmS[tr * 104 + 80 + (r & 3)] = (unsigned short)bfr(gval);
    }
    __syncthreads();

    // ==== team MFMA chain: 48 rows = 3 tiles, waves 0..2 ====
    if (wv < 3) {
        // L1: K pad 96 (3 chunks)
        f32x4 a1[4];
        #pragma unroll
        for (int nt = 0; nt < 4; ++nt) {
            const float b = t_b1[nt * 16 + lm];
            a1[nt] = (f32x4){b, b, b, b};
        }
        for (int c = 0; c < 3; ++c) {
            const short8 af = *(const short8*)(tmS + (wv * 16 + lm) * 104 + c * 32 + lg * 8);
            #pragma unroll
            for (int nt = 0; nt < 4; ++nt) {
                short8 wf;
                #pragma unroll
                for (int i = 0; i < 8; ++i) {
                    const int k = c * 32 + lg * 8 + i;
                    wf[i] = (short)((k < 84) ? bfr(t_w1[k * 64 + nt * 16 + lm]) : 0);
                }
                a1[nt] = __builtin_amdgcn_mfma_f32_16x16x32_bf16(af, wf, a1[nt], 0, 0, 0);
            }
        }
        #pragma unroll
        for (int nt = 0; nt < 4; ++nt)
            #pragma unroll
            for (int r = 0; r < 4; ++r)
                tmS[(wv * 16 + lg * 4 + r) * 104 + nt * 16 + lm] =
                    (unsigned short)bfr(fmaxf(a1[nt][r], 0.f));

        // L2: [48x64]@[64x64]
        f32x4 a2[4];
        #pragma unroll
        for (int nt = 0; nt < 4; ++nt) {
            const float b = t_b2[nt * 16 + lm];
            a2[nt] = (f32x4){b, b, b, b};
        }
        for (int c = 0; c < 2; ++c) {
            const short8 af = *(const short8*)(tmS + (wv * 16 + lm) * 104 + c * 32 + lg * 8);
            #pragma unroll
            for (int nt = 0; nt < 4; ++nt) {
                short8 wf;
                #pragma unroll
                for (int i = 0; i < 8; ++i) {
                    const int k = c * 32 + lg * 8 + i;
                    wf[i] = (short)bfr(t_w2[k * 64 + nt * 16 + lm]);
                }
                a2[nt] = __builtin_amdgcn_mfma_f32_16x16x32_bf16(af, wf, a2[nt], 0, 0, 0);
            }
        }
        #pragma unroll
        for (int nt = 0; nt < 4; ++nt)
            #pragma unroll
            for (int r = 0; r < 4; ++r)
                tmS[(wv * 16 + lg * 4 + r) * 104 + nt * 16 + lm] =
                    (unsigned short)bfr(fmaxf(a2[nt][r], 0.f));

        // L3: [48x64]@[64x16] linear -> sT
        const float b = t_b3[lm];
        f32x4 a3 = (f32x4){b, b, b, b};
        for (int c = 0; c < 2; ++c) {
            const short8 af = *(const short8*)(tmS + (wv * 16 + lm) * 104 + c * 32 + lg * 8);
            short8 wf;
            #pragma unroll
            for (int i = 0; i < 8; ++i) {
                const int k = c * 32 + lg * 8 + i;
                wf[i] = (short)bfr(t_w3[k * 16 + lm]);
            }
            a3 = __builtin_amdgcn_mfma_f32_16x16x32_bf16(af, wf, a3, 0, 0, 0);
        }
        #pragma unroll
        for (int r = 0; r < 4; ++r) {
            const int row = wv * 16 + lg * 4 + r;   // 0..47 = s*2+half
            if ((row >> 1) < vs)
                sT[(row >> 1) * 33 + (row & 1) * 16 + lm] = a3[r];
        }
    }
    __syncthreads();

    // ==== final MLP (32->16->16->2) + softmax, 1 lane/sample ====
    if (tid < vs) {
        const float* tr = sT + tid * 33;
        float g1[16];
        #pragma unroll
        for (int o = 0; o < 16; ++o) g1[o] = f_b1[o];
        #pragma unroll
        for (int k = 0; k < 32; ++k) {
            const float hk = tr[k];
            const float* wr = f_w1 + k * 16;
            #pragma unroll
            for (int o = 0; o < 16; ++o) g1[o] = fmaf(hk, wr[o], g1[o]);
        }
        float g2[16];
        #pragma unroll
        for (int o = 0; o < 16; ++o) g2[o] = f_b2[o];
        #pragma unroll
        for (int k = 0; k < 16; ++k) {
            const float hk = fmaxf(g1[k], 0.f);
            const float* wr = f_w2 + k * 16;
            #pragma unroll
            for (int o = 0; o < 16; ++o) g2[o] = fmaf(hk, wr[o], g2[o]);
        }
        float l0 = f_b3[0], l1 = f_b3[1];
        #pragma unroll
        for (int k = 0; k < 16; ++k) {
            const float hk = fmaxf(g2[k], 0.f);
            l0 = fmaf(hk, f_w3[2 * k], l0);
            l1 = fmaf(hk, f_w3[2 * k + 1], l1);
        }
        const float e = expf(l1 - l0);
        const float p0 = 1.f / (1.f + e);
        out[(size_t)(s0 + tid) * 2]     = p0;
        out[(size_t)(s0 + tid) * 2 + 1] = 1.f - p0;
    }
}

extern "C" void kernel_launch(void* const* d_in, const int* in_sizes, int n_in,
                              void* d_out, int out_size, void* d_ws, size_t ws_size,
                              hipStream_t stream) {
    (void)in_sizes; (void)n_in; (void)out_size; (void)d_ws; (void)ws_size;
    const float* x    = (const float*)d_in[0];
    const float* h_w1 = (const float*)d_in[1];  const float* h_b1 = (const float*)d_in[2];
    const float* h_w2 = (const float*)d_in[3];  const float* h_b2 = (const float*)d_in[4];
    const float* h_w3 = (const float*)d_in[5];  const float* h_b3 = (const float*)d_in[6];
    const float* c_w1 = (const float*)d_in[7];  const float* c_b1 = (const float*)d_in[8];
    const float* c_w2 = (const float*)d_in[9];  const float* c_b2 = (const float*)d_in[10];
    const float* c_w3 = (const float*)d_in[11]; const float* c_b3 = (const float*)d_in[12];
    const float* t_w1 = (const float*)d_in[13]; const float* t_b1 = (const float*)d_in[14];
    const float* t_w2 = (const float*)d_in[15]; const float* t_b2 = (const float*)d_in[16];
    const float* t_w3 = (const float*)d_in[17]; const float* t_b3 = (const float*)d_in[18];
    const float* f_w1 = (const float*)d_in[19]; const float* f_b1 = (const float*)d_in[20];
    const float* f_w2 = (const float*)d_in[21]; const float* f_b2 = (const float*)d_in[22];
    const float* f_w3 = (const float*)d_in[23]; const float* f_b3 = (const float*)d_in[24];
    float* out = (float*)d_out;

    const int grid = (NB + SPB - 1) / SPB;    // 2731
    fused_all<<<grid, 256, 0, stream>>>(
        x, h_w1, h_b1, h_w2, h_b2, h_w3, h_b3,
        c_w1, c_b1, c_w2, c_b2, c_w3, c_b3,
        t_w1, t_b1, t_w2, t_b2, t_w3, t_b3,
        f_w1, f_b1, f_w2, f_b2, f_w3, f_b3, out);
}

// Round 23
// 192.984 us; speedup vs baseline: 1.1676x; 1.0118x over previous
//
#include <hip/hip_runtime.h>
#include <hip/hip_bf16.h>
#include <math.h>

// Round 23: zero-barrier pairs loop.
//  r22 (full fusion) = 195us, latency-bound with the pairs loop's 5x3=15
//  block-wide barriers as the largest remaining serialization. Remap the
//  pool to the build's wave-private lane<->row map (lane (lg,lm) owns row
//  (wv+4*lg)*16+lm): build->L2/L3->pool->next-build all same-wave ordered
//  (r21 proved build->L2; compiler orders same-wave DS ops). Pairs region:
//  15 barriers -> 2. Everything else identical to r22.

#define NB 65536
#define SPB 24

typedef __attribute__((ext_vector_type(8))) short short8;
typedef __attribute__((ext_vector_type(4))) float f32x4;

__device__ __forceinline__ unsigned bfr(float f) {
    unsigned u = __float_as_uint(f);
    return (u + 0x7fffu + ((u >> 16) & 1u)) >> 16;
}
__device__ __forceinline__ unsigned pack_bf(float a, float b) {
    return bfr(a) | (bfr(b) << 16);
}
__device__ __forceinline__ float bf_lo(unsigned u) { return __uint_as_float(u << 16); }
__device__ __forceinline__ float bf_hi(unsigned u) { return __uint_as_float(u & 0xffff0000u); }

__global__ __launch_bounds__(256, 4) void fused_all(
    const float* __restrict__ x,
    const float* __restrict__ h_w1, const float* __restrict__ h_b1,
    const float* __restrict__ h_w2, const float* __restrict__ h_b2,
    const float* __restrict__ h_w3, const float* __restrict__ h_b3,
    const float* __restrict__ c_w1, const float* __restrict__ c_b1,
    const float* __restrict__ c_w2, const float* __restrict__ c_b2,
    const float* __restrict__ c_w3, const float* __restrict__ c_b3,
    const float* __restrict__ t_w1, const float* __restrict__ t_b1,
    const float* __restrict__ t_w2, const float* __restrict__ t_b2,
    const float* __restrict__ t_w3, const float* __restrict__ t_b3,
    const float* __restrict__ f_w1, const float* __restrict__ f_b1,
    const float* __restrict__ f_w2, const float* __restrict__ f_b2,
    const float* __restrict__ f_w3, const float* __restrict__ f_b3,
    float* __restrict__ out)
{
    // [0,4800)    acts u16 [240][40] (x / h1 / h2 / ho / u|v); later sT f32 [24][33]
    // [4800,7680) h1p u16 [240][24]; sC f32 stride-12 alias; later team
    //             staging u16 [48][104]
    __shared__ unsigned smem_u[7680];
    unsigned short* const acts = (unsigned short*)smem_u;
    unsigned* const h1pU = smem_u + 4800;
    unsigned short* const h1pU16 = (unsigned short*)(smem_u + 4800);
    float* const sC = (float*)(smem_u + 4800);              // stride 12 f32
    unsigned short* const tmS = (unsigned short*)(smem_u + 4800);  // team staging
    float* const sT = (float*)smem_u;                        // [24][33] f32

    const int tid = threadIdx.x;
    const int s0  = blockIdx.x * SPB;
    const int vs  = (NB - s0 < SPB) ? (NB - s0) : SPB;
    const int vr  = vs * 10;

    const int lane = tid & 63;
    const int wv   = tid >> 6;
    const int lm   = lane & 15;
    const int lg   = lane >> 4;
    const short8 zero8 = (short8){0,0,0,0,0,0,0,0};

    // ==== hero L1: [240x140]@[140x32], tid-striped staging ====
    f32x4 acc[4][2];
    #pragma unroll
    for (int t = 0; t < 4; ++t) {
        const float b0 = h_b1[lm], b1 = h_b1[16 + lm];
        acc[t][0] = (f32x4){b0, b0, b0, b0};
        acc[t][1] = (f32x4){b1, b1, b1, b1};
    }
    for (int c = 0; c < 5; ++c) {
        short8 w0f, w1f;
        #pragma unroll
        for (int i = 0; i < 8; ++i) {
            const int k = c * 32 + lg * 8 + i;
            w0f[i] = (short)((k < 140) ? bfr(h_w1[k * 32 + lm]) : 0);
            w1f[i] = (short)((k < 140) ? bfr(h_w1[k * 32 + 16 + lm]) : 0);
        }
        for (int j = tid; j < vr * 8; j += 256) {
            const int row = j >> 3, q = j & 7;
            unsigned lo = 0, hi = 0;
            if (c < 4 || q < 3) {
                const float4 v = *(const float4*)(
                    x + ((size_t)s0 * 10 + row) * 140 + c * 32 + q * 4);
                lo = pack_bf(v.x, v.y);
                hi = pack_bf(v.z, v.w);
            }
            smem_u[row * 20 + q * 2]     = lo;
            smem_u[row * 20 + q * 2 + 1] = hi;
        }
        __syncthreads();
        #pragma unroll
        for (int t = 0; t < 4; ++t) {
            const int tl = wv + 4 * t;
            if (tl < 15) {
                const short8 af = *(const short8*)(acts + (tl * 16 + lm) * 40 + lg * 8);
                acc[t][0] = __builtin_amdgcn_mfma_f32_16x16x32_bf16(af, w0f, acc[t][0], 0, 0, 0);
                acc[t][1] = __builtin_amdgcn_mfma_f32_16x16x32_bf16(af, w1f, acc[t][1], 0, 0, 0);
            }
        }
        __syncthreads();
    }
    // h1 relu -> own tiles (wave-private)
    #pragma unroll
    for (int t = 0; t < 4; ++t) {
        const int tl = wv + 4 * t;
        if (tl < 15) {
            #pragma unroll
            for (int nt = 0; nt < 2; ++nt)
                #pragma unroll
                for (int r = 0; r < 4; ++r)
                    acts[(tl * 16 + lg * 4 + r) * 40 + nt * 16 + lm] =
                        (unsigned short)bfr(fmaxf(acc[t][nt][r], 0.f));
        }
    }

    // ==== hero L2: wave-private, in-place ====
    {
        short8 af[4];
        #pragma unroll
        for (int t = 0; t < 4; ++t) {
            const int tl = wv + 4 * t;
            af[t] = (tl < 15) ? *(const short8*)(acts + (tl * 16 + lm) * 40 + lg * 8) : zero8;
        }
        short8 w0f, w1f;
        #pragma unroll
        for (int i = 0; i < 8; ++i) {
            const int k = lg * 8 + i;
            w0f[i] = (short)bfr(h_w2[k * 32 + lm]);
            w1f[i] = (short)bfr(h_w2[k * 32 + 16 + lm]);
        }
        #pragma unroll
        for (int t = 0; t < 4; ++t) {
            const float b0 = h_b2[lm], b1 = h_b2[16 + lm];
            f32x4 a20 = (f32x4){b0, b0, b0, b0};
            f32x4 a21 = (f32x4){b1, b1, b1, b1};
            const int tl = wv + 4 * t;
            if (tl < 15) {
                a20 = __builtin_amdgcn_mfma_f32_16x16x32_bf16(af[t], w0f, a20, 0, 0, 0);
                a21 = __builtin_amdgcn_mfma_f32_16x16x32_bf16(af[t], w1f, a21, 0, 0, 0);
                #pragma unroll
                for (int r = 0; r < 4; ++r) {
                    acts[(tl * 16 + lg * 4 + r) * 40 + lm]      =
                        (unsigned short)bfr(fmaxf(a20[r], 0.f));
                    acts[(tl * 16 + lg * 4 + r) * 40 + 16 + lm] =
                        (unsigned short)bfr(fmaxf(a21[r], 0.f));
                }
            }
        }
    }

    // ==== hero L3 -> acts cols 0..15 AND horeg (packed) ====
    unsigned horeg[4][2];
    {
        short8 af[4];
        #pragma unroll
        for (int t = 0; t < 4; ++t) {
            const int tl = wv + 4 * t;
            af[t] = (tl < 15) ? *(const short8*)(acts + (tl * 16 + lm) * 40 + lg * 8) : zero8;
        }
        short8 w3f;
        #pragma unroll
        for (int i = 0; i < 8; ++i)
            w3f[i] = (short)bfr(h_w3[(lg * 8 + i) * 16 + lm]);
        #pragma unroll
        for (int t = 0; t < 4; ++t) {
            const float b = h_b3[lm];
            f32x4 a3 = (f32x4){b, b, b, b};
            const int tl = wv + 4 * t;
            horeg[t][0] = 0; horeg[t][1] = 0;
            if (tl < 15) {
                a3 = __builtin_amdgcn_mfma_f32_16x16x32_bf16(af[t], w3f, a3, 0, 0, 0);
                #pragma unroll
                for (int r = 0; r < 4; ++r)
                    acts[(tl * 16 + lg * 4 + r) * 40 + lm] = (unsigned short)bfr(a3[r]);
                horeg[t][0] = pack_bf(a3[0], a3[1]);
                horeg[t][1] = pack_bf(a3[2], a3[3]);
            }
        }
    }

    // ==== uv via MFMA (wave-private) ====
    {
        short8 af[4];
        #pragma unroll
        for (int t = 0; t < 4; ++t) {
            const int tl = wv + 4 * t;
            af[t] = (tl < 15 && lg < 2)
                ? *(const short8*)(acts + (tl * 16 + lm) * 40 + lg * 8) : zero8;
        }
        short8 wuf, wvf;
        #pragma unroll
        for (int i = 0; i < 8; ++i) {
            const int k = lg * 8 + i;
            wuf[i] = (short)((k < 16) ? bfr(c_w1[k * 16 + lm]) : 0);
            wvf[i] = (short)((k < 16) ? bfr(c_w1[(16 + k) * 16 + lm]) : 0);
        }
        #pragma unroll
        for (int t = 0; t < 4; ++t) {
            const int tl = wv + 4 * t;
            if (tl < 15) {
                f32x4 au = (f32x4){0.f, 0.f, 0.f, 0.f};
                f32x4 av = (f32x4){0.f, 0.f, 0.f, 0.f};
                au = __builtin_amdgcn_mfma_f32_16x16x32_bf16(af[t], wuf, au, 0, 0, 0);
                av = __builtin_amdgcn_mfma_f32_16x16x32_bf16(af[t], wvf, av, 0, 0, 0);
                #pragma unroll
                for (int r = 0; r < 4; ++r) {
                    const int row = tl * 16 + lg * 4 + r;
                    acts[row * 40 + lm]      = (unsigned short)bfr(au[r]);
                    acts[row * 40 + 16 + lm] = (unsigned short)bfr(av[r]);
                }
            }
        }
    }
    __syncthreads();                 // u/v visible block-wide

    // ==== counter pairs: 5 passes, ZERO barriers (fully wave-private) ====
    float m00 = -1e30f, m01 = -1e30f, m02 = -1e30f, m03 = -1e30f;
    float m10 = -1e30f, m11 = -1e30f, m12 = -1e30f, m13 = -1e30f;
    short8 cw2f, cw3f;
    #pragma unroll
    for (int i = 0; i < 8; ++i) {
        const int k = lg * 8 + i;
        cw2f[i] = (short)((k < 16) ? bfr(c_w2[k * 16 + lm]) : 0);
        cw3f[i] = (short)((k < 16 && lm < 8) ? bfr(c_w3[k * 8 + lm]) : 0);
    }
    const int btl  = wv + 4 * lg;          // lane's build/pool tile
    const int prow = btl * 16 + lm;        // lane's row
    const int pt10 = prow % 10;            // row's t10 (sample-local pair idx)
    for (int p = 0; p < 5; ++p) {
        // build h1p row prow (wave-private; u/v stable cross-wave reads)
        if (btl < 15 && prow < vr) {
            const int s = prow / 10;
            const int pr = p * 10 + pt10;
            int i, j;
            if (pr < 25) { i = pr / 5; j = 5 + pr % 5; }
            else { const int q = pr - 25; i = 5 + q / 5; j = q % 5; }
            const unsigned* ur  = smem_u + (s * 10 + i) * 20;
            const unsigned* vr2 = smem_u + (s * 10 + j) * 20 + 8;
            #pragma unroll
            for (int cc = 0; cc < 8; ++cc) {
                const unsigned uu = ur[cc], vv = vr2[cc];
                const float a = fmaxf(bf_lo(uu) + bf_lo(vv) + c_b1[2 * cc], 0.f);
                const float b = fmaxf(bf_hi(uu) + bf_hi(vv) + c_b1[2 * cc + 1], 0.f);
                h1pU[prow * 12 + cc] = pack_bf(a, b);
            }
        }
        // counter L2+L3 on own tiles (same-wave DS order; no barrier)
        #pragma unroll
        for (int t = 0; t < 4; ++t) {
            const int tl = wv + 4 * t;
            if (tl < 15) {
                const short8 af2 = (lg < 2)
                    ? *(const short8*)(h1pU16 + (tl * 16 + lm) * 24 + lg * 8) : zero8;
                const float b2 = c_b2[lm];
                f32x4 a2 = (f32x4){b2, b2, b2, b2};
                a2 = __builtin_amdgcn_mfma_f32_16x16x32_bf16(af2, cw2f, a2, 0, 0, 0);
                #pragma unroll
                for (int r = 0; r < 4; ++r)
                    h1pU16[(tl * 16 + lg * 4 + r) * 24 + lm] =
                        (unsigned short)bfr(fmaxf(a2[r], 0.f));
                const short8 af3 = (lg < 2)
                    ? *(const short8*)(h1pU16 + (tl * 16 + lm) * 24 + lg * 8) : zero8;
                const float b3 = (lm < 8) ? c_b3[lm] : 0.f;
                f32x4 a3 = (f32x4){b3, b3, b3, b3};
                a3 = __builtin_amdgcn_mfma_f32_16x16x32_bf16(af3, cw3f, a3, 0, 0, 0);
                if (lm < 8) {
                    #pragma unroll
                    for (int r = 0; r < 4; ++r)
                        sC[(tl * 16 + lg * 4 + r) * 12 + lm] = a3[r];
                }
            }
        }
        // pool2 + running max on OWN row (same-wave DS order; no barrier)
        if (btl < 15 && prow < vr) {
            const float* cr = sC + prow * 12;
            const float p0 = fmaxf(cr[0], cr[1]);
            const float p1 = fmaxf(cr[2], cr[3]);
            const float p2 = fmaxf(cr[4], cr[5]);
            const float p3 = fmaxf(cr[6], cr[7]);
            const int pr = p * 10 + pt10;
            if (pr < 25) {
                m00 = fmaxf(m00, p0); m01 = fmaxf(m01, p1);
                m02 = fmaxf(m02, p2); m03 = fmaxf(m03, p3);
            } else {
                m10 = fmaxf(m10, p0); m11 = fmaxf(m11, p1);
                m12 = fmaxf(m12, p2); m13 = fmaxf(m13, p3);
            }
        }
    }

    // ==== stage per-row maxima (own row) -> barrier -> cross-wave reduce ====
    if (btl < 15 && prow < vr) {
        float* dst = sC + prow * 12;
        dst[0] = m00; dst[1] = m01; dst[2] = m02; dst[3] = m03;
        dst[4] = m10; dst[5] = m11; dst[6] = m12; dst[7] = m13;
    }
    __syncthreads();
    float gval = 0.f;
    if (tid < vs * 8) {
        const int s = tid >> 3, r = tid & 7;
        float mx = -1e30f;
        #pragma unroll
        for (int t = 0; t < 10; ++t)
            mx = fmaxf(mx, sC[(s * 10 + t) * 12 + r]);
        gval = mx;
    }
    __syncthreads();                 // sC reads done before team staging

    // ==== team staging [48][104]u16 over dead h1p/sC region ====
    for (int j = tid; j < 48 * 6; j += 256) {
        const int row = j / 6, q = 46 + j % 6;
        ((unsigned*)tmS)[row * 52 + q] = 0;
    }
    for (int j = tid; j < 48 * 4; j += 256) {
        const int row = j / 4, q = 42 + j % 4;
        ((unsigned*)tmS)[row * 52 + q] = 0;
    }
    #pragma unroll
    for (int t = 0; t < 4; ++t) {
        const int tl = wv + 4 * t;
        if (tl < 15) {
            #pragma unroll
            for (int r = 0; r < 4; ++r) {
                const int grow = tl * 16 + lg * 4 + r;
                if (grow < vr) {
                    const int s = grow / 10, h = grow % 10;
                    const int tr = s * 2 + (h >= 5);
                    const int col = (h % 5) * 16 + lm;
                    const unsigned pk = horeg[t][r >> 1];
                    const unsigned short hv = (unsigned short)((r & 1) ? (pk >> 16) : (pk & 0xffff));
                    tmS[tr * 104 + col] = hv;
                }
            }
        }
    }
    if (tid < vs * 8) {
        const int s = tid >> 3, r = tid & 7;
        const int tr = s * 2 + (r >> 2);
        tmS[tr * 104 + 80 + (r & 3)] = (unsigned short)bfr(gval);
    }
    __syncthreads();

    // ==== team MFMA chain: 48 rows = 3 tiles, waves 0..2 ====
    if (wv < 3) {
        f32x4 a1[4];
        #pragma unroll
        for (int nt = 0; nt < 4; ++nt) {
            const float b = t_b1[nt * 16 + lm];
            a1[nt] = (f32x4){b, b, b, b};
        }
        for (int c = 0; c < 3; ++c) {
            const short8 af = *(const short8*)(tmS + (wv * 16 + lm) * 104 + c * 32 + lg * 8);
            #pragma unroll
            for (int nt = 0; nt < 4; ++nt) {
                short8 wf;
                #pragma unroll
                for (int i = 0; i < 8; ++i) {
                    const int k = c * 32 + lg * 8 + i;
                    wf[i] = (short)((k < 84) ? bfr(t_w1[k * 64 + nt * 16 + lm]) : 0);
                }
                a1[nt] = __builtin_amdgcn_mfma_f32_16x16x32_bf16(af, wf, a1[nt], 0, 0, 0);
            }
        }
        #pragma unroll
        for (int nt = 0; nt < 4; ++nt)
            #pragma unroll
            for (int r = 0; r < 4; ++r)
                tmS[(wv * 16 + lg * 4 + r) * 104 + nt * 16 + lm] =
                    (unsigned short)bfr(fmaxf(a1[nt][r], 0.f));

        f32x4 a2[4];
        #pragma unroll
        for (int nt = 0; nt < 4; ++nt) {
            const float b = t_b2[nt * 16 + lm];
            a2[nt] = (f32x4){b, b, b, b};
        }
        for (int c = 0; c < 2; ++c) {
            const short8 af = *(const short8*)(tmS + (wv * 16 + lm) * 104 + c * 32 + lg * 8);
            #pragma unroll
            for (int nt = 0; nt < 4; ++nt) {
                short8 wf;
                #pragma unroll
                for (int i = 0; i < 8; ++i) {
                    const int k = c * 32 + lg * 8 + i;
                    wf[i] = (short)bfr(t_w2[k * 64 + nt * 16 + lm]);
                }
                a2[nt] = __builtin_amdgcn_mfma_f32_16x16x32_bf16(af, wf, a2[nt], 0, 0, 0);
            }
        }
        #pragma unroll
        for (int nt = 0; nt < 4; ++nt)
            #pragma unroll
            for (int r = 0; r < 4; ++r)
                tmS[(wv * 16 + lg * 4 + r) * 104 + nt * 16 + lm] =
                    (unsigned short)bfr(fmaxf(a2[nt][r], 0.f));

        const float b = t_b3[lm];
        f32x4 a3 = (f32x4){b, b, b, b};
        for (int c = 0; c < 2; ++c) {
            const short8 af = *(const short8*)(tmS + (wv * 16 + lm) * 104 + c * 32 + lg * 8);
            short8 wf;
            #pragma unroll
            for (int i = 0; i < 8; ++i) {
                const int k = c * 32 + lg * 8 + i;
                wf[i] = (short)bfr(t_w3[k * 16 + lm]);
            }
            a3 = __builtin_amdgcn_mfma_f32_16x16x32_bf16(af, wf, a3, 0, 0, 0);
        }
        #pragma unroll
        for (int r = 0; r < 4; ++r) {
            const int row = wv * 16 + lg * 4 + r;
            if ((row >> 1) < vs)
                sT[(row >> 1) * 33 + (row & 1) * 16 + lm] = a3[r];
        }
    }
    __syncthreads();

    // ==== final MLP (32->16->16->2) + softmax, 1 lane/sample ====
    if (tid < vs) {
        const float* tr = sT + tid * 33;
        float g1[16];
        #pragma unroll
        for (int o = 0; o < 16; ++o) g1[o] = f_b1[o];
        #pragma unroll
        for (int k = 0; k < 32; ++k) {
            const float hk = tr[k];
            const float* wr = f_w1 + k * 16;
            #pragma unroll
            for (int o = 0; o < 16; ++o) g1[o] = fmaf(hk, wr[o], g1[o]);
        }
        float g2[16];
        #pragma unroll
        for (int o = 0; o < 16; ++o) g2[o] = f_b2[o];
        #pragma unroll
        for (int k = 0; k < 16; ++k) {
            const float hk = fmaxf(g1[k], 0.f);
            const float* wr = f_w2 + k * 16;
            #pragma unroll
            for (int o = 0; o < 16; ++o) g2[o] = fmaf(hk, wr[o], g2[o]);
        }
        float l0 = f_b3[0], l1 = f_b3[1];
        #pragma unroll
        for (int k = 0; k < 16; ++k) {
            const float hk = fmaxf(g2[k], 0.f);
            l0 = fmaf(hk, f_w3[2 * k], l0);
            l1 = fmaf(hk, f_w3[2 * k + 1], l1);
        }
        const float e = expf(l1 - l0);
        const float p0 = 1.f / (1.f + e);
        out[(size_t)(s0 + tid) * 2]     = p0;
        out[(size_t)(s0 + tid) * 2 + 1] = 1.f - p0;
    }
}

extern "C" void kernel_launch(void* const* d_in, const int* in_sizes, int n_in,
                              void* d_out, int out_size, void* d_ws, size_t ws_size,
                              hipStream_t stream) {
    (void)in_sizes; (void)n_in; (void)out_size; (void)d_ws; (void)ws_size;
    const float* x    = (const float*)d_in[0];
    const float* h_w1 = (const float*)d_in[1];  const float* h_b1 = (const float*)d_in[2];
    const float* h_w2 = (const float*)d_in[3];  const float* h_b2 = (const float*)d_in[4];
    const float* h_w3 = (const float*)d_in[5];  const float* h_b3 = (const float*)d_in[6];
    const float* c_w1 = (const float*)d_in[7];  const float* c_b1 = (const float*)d_in[8];
    const float* c_w2 = (const float*)d_in[9];  const float* c_b2 = (const float*)d_in[10];
    const float* c_w3 = (const float*)d_in[11]; const float* c_b3 = (const float*)d_in[12];
    const float* t_w1 = (const float*)d_in[13]; const float* t_b1 = (const float*)d_in[14];
    const float* t_w2 = (const float*)d_in[15]; const float* t_b2 = (const float*)d_in[16];
    const float* t_w3 = (const float*)d_in[17]; const float* t_b3 = (const float*)d_in[18];
    const float* f_w1 = (const float*)d_in[19]; const float* f_b1 = (const float*)d_in[20];
    const float* f_w2 = (const float*)d_in[21]; const float* f_b2 = (const float*)d_in[22];
    const float* f_w3 = (const float*)d_in[23]; const float* f_b3 = (const float*)d_in[24];
    float* out = (float*)d_out;

    const int grid = (NB + SPB - 1) / SPB;    // 2731
    fused_all<<<grid, 256, 0, stream>>>(
        x, h_w1, h_b1, h_w2, h_b2, h_w3, h_b3,
        c_w1, c_b1, c_w2, c_b2, c_w3, c_b3,
        t_w1, t_b1, t_w2, t_b2, t_w3, t_b3,
        f_w1, f_b1, f_w2, f_b2, f_w3, f_b3, out);
}